// Round 1
// 621.328 us; speedup vs baseline: 1.0039x; 1.0039x over previous
//
#include <hip/hip_runtime.h>

// SparseUpsample: sparse transposed conv, kernel==stride==2 -> bijective map.
//   out_feats[(n*8+k)*128 + d] = sum_c feats[n][c] * W[k][c][d]
//     == GEMM C[100000,1024] = A[100000,256] @ W'[256,1024]
//   out_coords[(n*8+k)*3 + t] = 2*coords[n][t] + ((k >> (2-t)) & 1)
// d_out is read by the harness as one flat float32 buffer: feats region
// (102,400,000 f32) then coords region (2,400,000 stored as float values).
//
// R1 changes vs 623us baseline:
//  - Bs LDS staging removed: Wt (512 KB) is L2-resident; B fragments are read
//    directly from global. Removes both per-kv barriers, LDS 132->67.6 KB
//    -> 2 blocks/CU (2 waves/SIMD) instead of 1 wave/SIMD.
//  - MFMA operands swapped (mfma(b,a,acc)): D's 4 regs/lane become 4
//    consecutive output COLUMNS -> float4 epilogue stores (was 64 scalar dw).
//  - Non-temporal output stores: 410 MB streamed, never re-read; keeps Wt in L2.

#define N_PTS  100000
#define CIN    256
#define COUT   128
#define KVOL   8
#define NCOL   1024                       // KVOL * COUT
#define MT     128                        // rows per block
#define LDA    264                        // padded LDS row, bf16 units (+8 -> 2-way max on b128 reads)
#define FEATS_OUT_ELEMS 102400000         // N_PTS * KVOL * COUT
#define COORD_OUT_ELEMS 2400000           // N_PTS * KVOL * 3

typedef __bf16 bf16x8 __attribute__((ext_vector_type(8)));
typedef float  f32x4  __attribute__((ext_vector_type(4)));
typedef unsigned short u16;
typedef u16 u16x8 __attribute__((ext_vector_type(8)));
typedef u16 u16x4 __attribute__((ext_vector_type(4)));

__device__ __forceinline__ u16 f2bf(float x) {   // fp32 -> bf16, round-nearest-even
  unsigned u = __builtin_bit_cast(unsigned, x);
  u += 0x7FFFu + ((u >> 16) & 1u);
  return (u16)(u >> 16);
}

// ---- prep: Wt[k][d][c] = bf16(W[k][c][d])  (B^T layout so GEMM B-frag reads are
//      contiguous 16B along K).  1 MB read / 0.5 MB write, LDS 32x32 transpose.
__global__ void prep_w_kernel(const float* __restrict__ W, u16* __restrict__ Wt) {
  __shared__ float t[32][33];
  int bx = blockIdx.x;              // 256 blocks: k(8) x ctile(8) x dtile(4)
  int k  = bx >> 5;
  int ct = (bx & 31) >> 2;
  int dt = bx & 3;
  int c0 = ct * 32, d0 = dt * 32;
  int tx = threadIdx.x & 31, ty = threadIdx.x >> 5;   // 32 x 8
  const float* Wk = W + (size_t)k * (CIN * COUT);
#pragma unroll
  for (int i = 0; i < 4; ++i) {
    int c = ty + i * 8;
    t[c][tx] = Wk[(size_t)(c0 + c) * COUT + d0 + tx];   // coalesced along d
  }
  __syncthreads();
  u16* Wtk = Wt + (size_t)k * (CIN * COUT);
#pragma unroll
  for (int i = 0; i < 4; ++i) {
    int d = ty + i * 8;
    Wtk[(size_t)(d0 + d) * CIN + c0 + tx] = f2bf(t[tx][d]); // coalesced along c
  }
}

// ---- coords: stored as FLOAT values (harness reads whole d_out as f32)
__global__ void coords_kernel(const int* __restrict__ coords, float* __restrict__ outc) {
  int idx = blockIdx.x * 256 + threadIdx.x;
  if (idx >= COORD_OUT_ELEMS) return;
  int n = idx / 24;
  int r = idx - n * 24;
  int k = r / 3;
  int t = r - k * 3;
  int bit = (k >> (2 - t)) & 1;
  outc[idx] = (float)(2 * coords[n * 3 + t] + bit);
}

// ---- GEMM: block = 128-row M-tile; A staged once (fp32->bf16) in LDS, B read
//      directly from global (L2-resident 512 KB), no barriers in the kv loop.
__global__ __launch_bounds__(256, 2) void gemm_kernel(const float* __restrict__ feats,
                                                      const u16* __restrict__ Wt,
                                                      float* __restrict__ out) {
  __shared__ u16 As[MT * LDA];     // 67,584 B -> 2 blocks/CU
  const int tid = threadIdx.x;
  const int m0  = blockIdx.x * MT;

  // stage A: 128x256 fp32 -> bf16 LDS, coalesced float4 loads (32/thread)
#pragma unroll
  for (int i = 0; i < 32; ++i) {
    int f   = tid + i * 256;        // float4 id in [0,8192)
    int row = f >> 6;               // 64 float4 per row
    int c4  = (f & 63) << 2;
    int gr  = m0 + row;
    float4 v = make_float4(0.f, 0.f, 0.f, 0.f);
    if (gr < N_PTS) v = *(const float4*)(feats + (size_t)gr * CIN + c4);
    u16x4 p;
    p.x = f2bf(v.x); p.y = f2bf(v.y); p.z = f2bf(v.z); p.w = f2bf(v.w);
    *(u16x4*)&As[row * LDA + c4] = p;
  }
  __syncthreads();                  // only barrier in the kernel

  const int lane = tid & 63;
  const int wave = tid >> 6;
  const int wrow = (wave & 1) << 6;   // wave's 64x64 quadrant
  const int wcol = (wave >> 1) << 6;
  const int lr   = lane & 15;
  const int quad = lane >> 4;

  for (int kv = 0; kv < KVOL; ++kv) {
    const u16* Wk = Wt + kv * (CIN * COUT);

    f32x4 acc[4][4];
#pragma unroll
    for (int r = 0; r < 4; ++r)
#pragma unroll
      for (int c = 0; c < 4; ++c)
        acc[r][c] = f32x4{0.f, 0.f, 0.f, 0.f};

#pragma unroll
    for (int ks = 0; ks < 8; ++ks) {  // K = 256 = 8 x 32
      const int ko = ks * 32 + quad * 8;
      bf16x8 a[4], b[4];
#pragma unroll
      for (int r = 0; r < 4; ++r)
        a[r] = __builtin_bit_cast(bf16x8, *(const u16x8*)&As[(wrow + r * 16 + lr) * LDA + ko]);
#pragma unroll
      for (int c = 0; c < 4; ++c)
        b[c] = __builtin_bit_cast(bf16x8,
                 *(const u16x8*)(Wk + (size_t)(wcol + c * 16 + lr) * CIN + ko));
      // swapped operands: D[row<-b's n, col<-a's m]; lane&15 = output row,
      // quad*4+reg = output col -> 4 regs are 4 consecutive columns.
#pragma unroll
      for (int r = 0; r < 4; ++r)
#pragma unroll
        for (int c = 0; c < 4; ++c)
          acc[r][c] = __builtin_amdgcn_mfma_f32_16x16x32_bf16(b[c], a[r], acc[r][c], 0, 0, 0);
    }

    // store this 128x128 subtile: row = m-tile + lr, col = quad*4 + reg (f32x4)
    const int cb = (kv << 7) + wcol + (quad << 2);
#pragma unroll
    for (int r = 0; r < 4; ++r) {
      const int row = m0 + wrow + r * 16 + lr;
      if (row < N_PTS) {
        float* orow = out + (size_t)row * NCOL + cb;
#pragma unroll
        for (int c = 0; c < 4; ++c)
          __builtin_nontemporal_store(acc[r][c], (f32x4*)(orow + c * 16));
      }
    }
  }
}

extern "C" void kernel_launch(void* const* d_in, const int* in_sizes, int n_in,
                              void* d_out, int out_size, void* d_ws, size_t ws_size,
                              hipStream_t stream) {
  const float* feats  = (const float*)d_in[0];   // [100000, 256] f32
  const int*   coords = (const int*)d_in[1];     // [100000, 3]   i32
  const float* W      = (const float*)d_in[2];   // [8, 256, 128] f32
  float* out = (float*)d_out;
  u16*   Wt  = (u16*)d_ws;                       // 512 KB bf16 B^T

  prep_w_kernel<<<256, 256, 0, stream>>>(W, Wt);
  coords_kernel<<<(COORD_OUT_ELEMS + 255) / 256, 256, 0, stream>>>(coords, out + (size_t)FEATS_OUT_ELEMS);
  gemm_kernel<<<(N_PTS + MT - 1) / MT, 256, 0, stream>>>(feats, Wt, out);
}